// Round 8
// baseline (63.225 us; speedup 1.0000x reference)
//
#include <hip/hip_runtime.h>
#include <cfloat>

#define MEMN 8192
#define FEATD 512
#define BATCH 16
#define NBLK 512
#define MAGICF 0x4D474331u

static constexpr float TAU_NEW_C = 0.85f;
static constexpr float D_MIN_C  = 1.5f;
static constexpr float ALPHA_C  = 0.5f;
static constexpr float EPS_C    = 1e-8f;

__device__ __forceinline__ int brev4(int l) {
  return ((l & 1) << 3) | ((l & 2) << 1) | ((l & 4) >> 1) | ((l & 8) >> 3);
}
__device__ __forceinline__ int brev3(int l) {
  return ((l & 1) << 2) | (l & 2) | ((l & 4) >> 2);
}
__device__ __forceinline__ float dot8(const float4& a0, const float4& a1,
                                      const float4& b0, const float4& b1) {
  return a0.x*b0.x + a0.y*b0.y + a0.z*b0.z + a0.w*b0.w
       + a1.x*b1.x + a1.y*b1.y + a1.z*b1.z + a1.w*b1.w;
}

// Reduce 8 per-lane partials across the wave; lane l ends with the full-wave
// sum of acc[brev3(l&7)]. All indices compile-time.
__device__ __forceinline__ float tree_reduce8(float acc[8], int lane) {
  #pragma unroll
  for (int k = 0; k < 4; ++k) {
    const bool hi = (lane & 1);
    const float mine = hi ? acc[k + 4] : acc[k];
    const float send = hi ? acc[k] : acc[k + 4];
    acc[k] = mine + __shfl_xor(send, 1);
  }
  #pragma unroll
  for (int k = 0; k < 2; ++k) {
    const bool hi = (lane & 2);
    const float mine = hi ? acc[k + 2] : acc[k];
    const float send = hi ? acc[k] : acc[k + 2];
    acc[k] = mine + __shfl_xor(send, 2);
  }
  {
    const bool hi = (lane & 4);
    const float mine = hi ? acc[1] : acc[0];
    const float send = hi ? acc[0] : acc[1];
    acc[0] = mine + __shfl_xor(send, 4);
  }
  acc[0] += __shfl_xor(acc[0], 8);
  acc[0] += __shfl_xor(acc[0], 16);
  acc[0] += __shfl_xor(acc[0], 32);
  return acc[0];
}

// Reduce 16 per-lane partials; lane l ends with sum of acc[brev4(l&15)].
__device__ __forceinline__ float tree_reduce16(float acc[BATCH], int lane) {
  #pragma unroll
  for (int k = 0; k < 8; ++k) {
    const bool hi = (lane & 1);
    const float mine = hi ? acc[k + 8] : acc[k];
    const float send = hi ? acc[k] : acc[k + 8];
    acc[k] = mine + __shfl_xor(send, 1);
  }
  #pragma unroll
  for (int k = 0; k < 4; ++k) {
    const bool hi = (lane & 2);
    const float mine = hi ? acc[k + 4] : acc[k];
    const float send = hi ? acc[k] : acc[k + 4];
    acc[k] = mine + __shfl_xor(send, 2);
  }
  #pragma unroll
  for (int k = 0; k < 2; ++k) {
    const bool hi = (lane & 4);
    const float mine = hi ? acc[k + 2] : acc[k];
    const float send = hi ? acc[k] : acc[k + 2];
    acc[k] = mine + __shfl_xor(send, 4);
  }
  {
    const bool hi = (lane & 8);
    const float mine = hi ? acc[1] : acc[0];
    const float send = hi ? acc[0] : acc[1];
    acc[0] = mine + __shfl_xor(send, 8);
  }
  acc[0] += __shfl_xor(acc[0], 16);
  acc[0] += __shfl_xor(acc[0], 32);
  return acc[0];
}

// ws: pv[16][256] f, pi[16][256] i, pre4[64] f, hnw[16] f, cross[16][16] f,
//     flags[512] u32
//
// Single kernel, grid 512: blocks [0,256) score steps 0-7 (rows ≡ bloc mod 256),
// [256,512) steps 8-15. Completion: per-block release-store to flags[b]
// (distinct addresses -> no RMW serialization; R5's flat same-address atomicInc
// chain cost ~22us). Block 0 spin-polls flags with agent-scope loads, clears
// them (next replay starts clean; 0xAA poison != MAGIC covers the first), then
// runs the val / fallback phase.
__global__ __launch_bounds__(256, 2) void fused_k(
    const float* __restrict__ h_t, const float* __restrict__ posin,
    const unsigned char* __restrict__ dones, const int* __restrict__ lastv,
    const float* __restrict__ feat, const float* __restrict__ posns,
    const float* __restrict__ adj, const int* __restrict__ num_nodes,
    const int* __restrict__ ptr_in,
    float* __restrict__ pv, int* __restrict__ pi, float* __restrict__ pre4,
    float* __restrict__ hnw, float* __restrict__ cross,
    unsigned* flags, float* __restrict__ out)
{
  const int b = blockIdx.x;
  const int half = b >> 8;        // 0: steps 0-7, 1: steps 8-15
  const int bloc = b & 255;
  const int soff = half * 8;
  const int tid = threadIdx.x;
  const int wave = tid >> 6, lane = tid & 63;
  const int n0 = *num_nodes;

  __shared__ float sv[4][8]; __shared__ int si[4][8];
  __shared__ float red4[4];

  // block 0: prefetch the 16 speculative adjacency probes early (val phase input)
  float adjval = 1.f; int lastp = -1;
  if (b == 0 && tid < BATCH) {
    lastp = lastv[tid];
    if (lastp != -1) {
      const int lc = min(max(lastp, 0), MEMN - 1);
      adjval = adj[(size_t)min(n0 + tid, MEMN - 1) * MEMN + lc];
    }
  }

  // this lane's 8-float slice of its half's 8 h vectors (64 VGPRs)
  float4 hA[8], hB[8];
  #pragma unroll
  for (int i = 0; i < 8; ++i) {
    const float4* hp = (const float4*)(h_t + (i + soff) * FEATD + lane * 8);
    hA[i] = hp[0]; hB[i] = hp[1];
  }

  // ---- score phase: rows ≡ bloc (mod 256); no LDS in the inner loop ----
  float bestv = -FLT_MAX; int besti = 0x7fffffff;  // lane tracks step brev3(lane&7)
  #pragma unroll
  for (int j = 0; j < 4; ++j) {
    const int row = bloc + ((j * 4 + wave) << 8);  // ascending per wave
    if (row >= n0) break;
    const float4* fr = (const float4*)(feat + (size_t)row * FEATD + lane * 8);
    const float4 a0 = fr[0], a1 = fr[1];
    float acc[8];
    #pragma unroll
    for (int i = 0; i < 8; ++i) acc[i] = dot8(a0, a1, hA[i], hB[i]);
    float sq = dot8(a0, a1, a0, a1);
    #pragma unroll
    for (int m = 1; m <= 32; m <<= 1) sq += __shfl_xor(sq, m);
    const float dtot = tree_reduce8(acc, lane);
    const float v = dtot / fmaxf(sqrtf(sq), EPS_C);
    if (v > bestv) { bestv = v; besti = row; }  // strict >: lowest row wins
  }
  if (lane < 8) { sv[wave][brev3(lane)] = bestv; si[wave][brev3(lane)] = besti; }
  __syncthreads();
  if (tid < 8) {
    float v = sv[0][tid]; int ix = si[0][tid];
    #pragma unroll
    for (int w = 1; w < 4; ++w)
      if (sv[w][tid] > v || (sv[w][tid] == v && si[w][tid] < ix)) { v = sv[w][tid]; ix = si[w][tid]; }
    pv[(tid + soff) * 256 + bloc] = v; pi[(tid + soff) * 256 + bloc] = ix;
  }

  // ---- extra duties (half 0 only) ----
  if (b < 64) {
    // quarter-rowsum of adjacency row n0 + (b>>2), quarter (b&3)
    const int row = min(n0 + (b >> 2), MEMN - 1);
    const float4* r4 = (const float4*)(adj + (size_t)row * MEMN + (size_t)(b & 3) * 2048);
    const float4 q0 = r4[tid], q1 = r4[tid + 256];
    float s = q0.x+q0.y+q0.z+q0.w + q1.x+q1.y+q1.z+q1.w;
    #pragma unroll
    for (int m = 1; m <= 32; m <<= 1) s += __shfl_xor(s, m);
    if (lane == 0) red4[wave] = s;
    __syncthreads();
    if (tid == 0) pre4[b] = red4[0] + red4[1] + red4[2] + red4[3];
  } else if (b >= 64 && b < 80) {
    // cross-sims column j and ||h_j||; h[0..7] from regs, h[8..15] from L2-hot h_t
    const int j = b - 64;
    if (wave == 0) {
      const float4* cp = (const float4*)(h_t + j * FEATD + lane * 8);
      const float4 c0 = cp[0], c1 = cp[1];
      float acc[BATCH];
      #pragma unroll
      for (int i = 0; i < 8; ++i) acc[i] = dot8(c0, c1, hA[i], hB[i]);
      #pragma unroll
      for (int i = 8; i < 16; ++i) {
        const float4* bp = (const float4*)(h_t + i * FEATD + lane * 8);
        acc[i] = dot8(c0, c1, bp[0], bp[1]);
      }
      const float d = tree_reduce16(acc, lane);   // lane holds dot(h_brev4(lane), h_j)
      const float djj = __shfl(d, brev4(j));
      const float inv = 1.f / fmaxf(sqrtf(djj), EPS_C);
      if (lane == 0) hnw[j] = sqrtf(djj);
      if (lane < BATCH) cross[brev4(lane) * 16 + j] = d * inv;
    }
  }

  // ---- completion: distinct-address release flags (no RMW chain) ----
  __threadfence();
  __syncthreads();
  if (tid == 0)
    __hip_atomic_store(&flags[b], MAGICF, __ATOMIC_RELEASE, __HIP_MEMORY_SCOPE_AGENT);
  if (b != 0) return;

  // ---- block 0: spin until all 512 flags set (workers never wait on us) ----
  for (;;) {
    const unsigned f1 = __hip_atomic_load(&flags[tid],       __ATOMIC_RELAXED, __HIP_MEMORY_SCOPE_AGENT);
    const unsigned f2 = __hip_atomic_load(&flags[tid + 256], __ATOMIC_RELAXED, __HIP_MEMORY_SCOPE_AGENT);
    if (__syncthreads_and((f1 == MAGICF) && (f2 == MAGICF))) break;
  }
  __threadfence();  // acquire: all workers' ws writes now visible
  // clear for the next replay (agent scope so it reaches the coherence point)
  __hip_atomic_store(&flags[tid],       0u, __ATOMIC_RELAXED, __HIP_MEMORY_SCOPE_AGENT);
  __hip_atomic_store(&flags[tid + 256], 0u, __ATOMIC_RELAXED, __HIP_MEMORY_SCOPE_AGENT);

  // ---- val phase ----
  __shared__ float wv[BATCH][4]; __shared__ int wi[BATCH][4];
  __shared__ float preS[BATCH]; __shared__ float s_outv[BATCH];
  __shared__ int s_valid;

  if (tid < BATCH)
    preS[tid] = pre4[tid*4+0] + pre4[tid*4+1] + pre4[tid*4+2] + pre4[tid*4+3];

  #pragma unroll
  for (int s = 0; s < BATCH; ++s) {
    float bv = pv[s * 256 + tid]; int bi = pi[s * 256 + tid];
    #pragma unroll
    for (int off = 32; off; off >>= 1) {
      const float v2 = __shfl_down(bv, off);
      const int   i2 = __shfl_down(bi, off);
      if (v2 > bv || (v2 == bv && i2 < bi)) { bv = v2; bi = i2; }
    }
    if (lane == 0) { wv[s][wave] = bv; wi[s][wave] = bi; }
  }
  __syncthreads();
  int ok = 1;
  if (tid < BATCH) {
    const int s = tid;
    float bv = wv[s][0]; int bi = wi[s][0];
    #pragma unroll
    for (int w = 1; w < 4; ++w)
      if (wv[s][w] > bv || (wv[s][w] == bv && wi[s][w] < bi)) { bv = wv[s][w]; bi = wi[s][w]; }
    for (int j = 0; j < s; ++j) {  // speculative new rows n0+j (higher idx: strict >)
      const float cv2 = cross[s * 16 + j];
      if (cv2 > bv) { bv = cv2; bi = n0 + j; }
    }
    if (bi == 0x7fffffff) ok = 0;
    else {
      const float max_sim = bv / fmaxf(hnw[s], EPS_C);
      float px, py, pz;
      if (bi >= n0) { const float* pp = posin + (size_t)(bi - n0) * 3; px = pp[0]; py = pp[1]; pz = pp[2]; }
      else          { const float* pp = posns + (size_t)bi * 3;        px = pp[0]; py = pp[1]; pz = pp[2]; }
      const float dx = posin[s * 3 + 0] - px;
      const float dy = posin[s * 3 + 1] - py;
      const float dz = posin[s * 3 + 2] - pz;
      const float dist = sqrtf(dx * dx + dy * dy + dz * dz);
      const bool should_add = (max_sim < TAU_NEW_C) || (dist > D_MIN_C);
      // validity also needs lastv[s] < n0 so prior edges provably never touch row n0+s
      ok = (!dones[s]) && should_add && (lastp == -1 || lastp < n0);
      float o = preS[s];
      if (lastp != -1 && lastp != n0 + s) { if (adjval == 0.f) o += 1.f; }
      s_outv[s] = o;
    }
  }
  const unsigned long long m = __ballot(tid < BATCH ? ok : 1);
  if (tid == 0) s_valid = ((~m == 0ull) && (n0 >= 1) && (n0 + BATCH <= MEMN)) ? 1 : 0;
  __syncthreads();
  if (s_valid) { if (tid < BATCH) out[tid] = s_outv[tid]; return; }

  // ---------------- generic sequential fallback (rare path) ----------------
  __shared__ float mf[16][FEATD];
  __shared__ float mp[16][3];
  __shared__ int   midx[16];
  __shared__ float shF[FEATD];
  __shared__ float rvF[256]; __shared__ int riF[256];
  __shared__ int   edges[64][2];
  __shared__ int   s_n, s_p, s_ec, s_mc;
  __shared__ int   s_done, s_widx, s_ema, s_src, s_dst, s_fb;
  __shared__ float s_delta, s_sum;
  if (tid == 0) { s_n = n0; s_p = *ptr_in; s_ec = 0; s_mc = 0; }
  __syncthreads();

  for (int step = 0; step < BATCH; ++step) {
    for (int k = tid; k < FEATD; k += 256) shF[k] = h_t[step * FEATD + k];
    __syncthreads();
    const int n_cur = s_n, mc = s_mc;

    float bv = -FLT_MAX; int bi = 0x7fffffff;
    for (int r = wave; r < n_cur; r += 4) {  // ascending per wave
      const float* src = feat + (size_t)r * FEATD;
      for (int k = 0; k < 16; ++k)
        if (k < mc && midx[k] == r) src = mf[k];
      float dot = 0.f, sq2 = 0.f;
      for (int e = lane; e < FEATD; e += 64) {
        const float a = src[e], b2 = shF[e];
        dot += a * b2; sq2 += a * a;
      }
      #pragma unroll
      for (int off = 32; off; off >>= 1) {
        dot += __shfl_down(dot, off);
        sq2 += __shfl_down(sq2, off);
      }
      if (lane == 0) {
        const float vv = dot / fmaxf(sqrtf(sq2), EPS_C);
        if (vv > bv) { bv = vv; bi = r; }
      }
    }
    if (lane == 0) { rvF[wave] = bv; riF[wave] = bi; }
    __syncthreads();

    if (tid == 0) {
      float fbv = rvF[0]; int fbi = riF[0];
      for (int w = 1; w < 4; ++w)
        if (rvF[w] > fbv || (rvF[w] == fbv && riF[w] < fbi)) { fbv = rvF[w]; fbi = riF[w]; }
      const int n = s_n, p = s_p;
      int best; float max_sim;
      if (n < 1) { best = 0; max_sim = -2.0f; }
      else { best = fbi; max_sim = fbv / fmaxf(hnw[step], EPS_C); }
      int bsrc = -1;
      for (int k = 0; k < s_mc; ++k) if (midx[k] == best) bsrc = k;
      float pbx, pby, pbz;
      if (bsrc >= 0) { pbx = mp[bsrc][0]; pby = mp[bsrc][1]; pbz = mp[bsrc][2]; }
      else { const float* pb = posns + (size_t)best * 3; pbx = pb[0]; pby = pb[1]; pbz = pb[2]; }
      const float dx = posin[step * 3 + 0] - pbx;
      const float dy = posin[step * 3 + 1] - pby;
      const float dz = posin[step * 3 + 2] - pbz;
      const float dist = sqrtf(dx * dx + dy * dy + dz * dz);
      const int done = dones[step] ? 1 : 0;
      const bool empty = (n < 1);
      const bool should_add = (max_sim < TAU_NEW_C) || (dist > D_MIN_C);
      const bool has_room = (n < MEMN);
      const int widx = empty ? 0 : (should_add ? (has_room ? n : p) : best);
      const bool ema = (!empty) && (!should_add);
      int srcs = -1;
      for (int k = 0; k < s_mc; ++k) if (midx[k] == widx) srcs = k;
      int dsts = srcs;
      if (!done) {
        if (srcs < 0) { dsts = s_mc; midx[dsts] = widx; s_mc = dsts + 1; }
        if (empty || (should_add && has_room)) s_n = n + 1;
        if ((!empty) && should_add && (!has_room)) s_p = (p + 1) % MEMN;
        const int last = lastv[step];
        if (last != -1 && last != widx) {
          const int lc = min(max(last, 0), MEMN - 1);
          const int ec = s_ec;
          edges[ec][0] = lc;   edges[ec][1] = widx;
          edges[ec + 1][0] = widx; edges[ec + 1][1] = lc;
          s_ec = ec + 2;
        }
      }
      s_done = done; s_widx = widx; s_ema = ema ? 1 : 0; s_src = srcs; s_dst = dsts;
      s_delta = 0.f;
      s_fb = 0;
      if (!done) {
        if (widx >= n0 && widx < n0 + BATCH) s_sum = preS[widx - n0];
        else s_fb = 1;
      }
    }
    __syncthreads();

    if (!s_done) {
      const int widx = s_widx;
      float* dstf = mf[s_dst];
      if (s_ema) {
        const float* srcf = (s_src >= 0) ? mf[s_src] : (feat + (size_t)widx * FEATD);
        for (int k = tid; k < FEATD; k += 256)
          dstf[k] = ALPHA_C * srcf[k] + (1.f - ALPHA_C) * shF[k];
      } else {
        for (int k = tid; k < FEATD; k += 256) dstf[k] = shF[k];
      }
      if (tid < 3) {
        const float sp = (s_src >= 0) ? mp[s_src][tid] : posns[(size_t)widx * 3 + tid];
        mp[s_dst][tid] = s_ema ? (ALPHA_C * sp + (1.f - ALPHA_C) * posin[step * 3 + tid])
                               : posin[step * 3 + tid];
      }
      if (tid < s_ec) {
        const int cur = widx;
        if (edges[tid][0] == cur) {
          const int c = edges[tid][1];
          bool dup = false;
          for (int e2 = 0; e2 < tid; ++e2)
            if (edges[e2][0] == cur && edges[e2][1] == c) dup = true;
          if (!dup && adj[(size_t)cur * MEMN + c] == 0.f) atomicAdd(&s_delta, 1.f);
        }
      }
    }
    __syncthreads();

    if (s_fb) {
      const float* rowp = adj + (size_t)s_widx * MEMN;
      float s = 0.f;
      for (int k = tid; k < MEMN; k += 256) s += rowp[k];
      rvF[tid] = s;
      __syncthreads();
      for (int st = 128; st; st >>= 1) { if (tid < st) rvF[tid] += rvF[tid + st]; __syncthreads(); }
      if (tid == 0) s_sum = rvF[0];
      __syncthreads();
    }
    if (tid == 0) out[step] = s_done ? 0.f : (s_sum + s_delta);
    __syncthreads();
  }
}

extern "C" void kernel_launch(void* const* d_in, const int* in_sizes, int n_in,
                              void* d_out, int out_size, void* d_ws, size_t ws_size,
                              hipStream_t stream) {
  const float*         h_t       = (const float*)d_in[0];
  const float*         cur_pos   = (const float*)d_in[1];
  const unsigned char* dones     = (const unsigned char*)d_in[2];
  const float*         node_feat = (const float*)d_in[3];
  const float*         node_pos  = (const float*)d_in[4];
  const float*         adj       = (const float*)d_in[5];
  const int*           num_nodes = (const int*)d_in[6];
  const int*           ptr_in    = (const int*)d_in[7];
  const int*           lastv     = (const int*)d_in[8];
  float* out = (float*)d_out;

  float*    pv    = (float*)d_ws;               // 16*256
  int*      pi    = (int*)(pv + BATCH * 256);   // 16*256
  float*    pre4  = (float*)(pi + BATCH * 256); // 64
  float*    hnw   = pre4 + 64;                  // 16
  float*    cross = hnw + BATCH;                // 256
  unsigned* flags = (unsigned*)(cross + 256);   // 512

  fused_k<<<NBLK, 256, 0, stream>>>(h_t, cur_pos, dones, lastv, node_feat, node_pos,
                                    adj, num_nodes, ptr_in,
                                    pv, pi, pre4, hnw, cross, flags, out);
}

// Round 9
// 26.244 us; speedup vs baseline: 2.4091x; 2.4091x over previous
//
#include <hip/hip_runtime.h>
#include <cfloat>

#define MEMN 8192
#define FEATD 512
#define BATCH 16

static constexpr float TAU_NEW_C = 0.85f;
static constexpr float D_MIN_C  = 1.5f;
static constexpr float ALPHA_C  = 0.5f;
static constexpr float EPS_C    = 1e-8f;

__device__ __forceinline__ int brev4(int l) {
  return ((l & 1) << 3) | ((l & 2) << 1) | ((l & 4) >> 1) | ((l & 8) >> 3);
}
__device__ __forceinline__ int brev3(int l) {
  return ((l & 1) << 2) | (l & 2) | ((l & 4) >> 2);
}
__device__ __forceinline__ float dot8(const float4& a0, const float4& a1,
                                      const float4& b0, const float4& b1) {
  return a0.x*b0.x + a0.y*b0.y + a0.z*b0.z + a0.w*b0.w
       + a1.x*b1.x + a1.y*b1.y + a1.z*b1.z + a1.w*b1.w;
}

// Reduce 8 per-lane partials across the wave; lane l ends with the full-wave
// sum of acc[brev3(l&7)]. All indices compile-time.
__device__ __forceinline__ float tree_reduce8(float acc[8], int lane) {
  #pragma unroll
  for (int k = 0; k < 4; ++k) {
    const bool hi = (lane & 1);
    const float mine = hi ? acc[k + 4] : acc[k];
    const float send = hi ? acc[k] : acc[k + 4];
    acc[k] = mine + __shfl_xor(send, 1);
  }
  #pragma unroll
  for (int k = 0; k < 2; ++k) {
    const bool hi = (lane & 2);
    const float mine = hi ? acc[k + 2] : acc[k];
    const float send = hi ? acc[k] : acc[k + 2];
    acc[k] = mine + __shfl_xor(send, 2);
  }
  {
    const bool hi = (lane & 4);
    const float mine = hi ? acc[1] : acc[0];
    const float send = hi ? acc[0] : acc[1];
    acc[0] = mine + __shfl_xor(send, 4);
  }
  acc[0] += __shfl_xor(acc[0], 8);
  acc[0] += __shfl_xor(acc[0], 16);
  acc[0] += __shfl_xor(acc[0], 32);
  return acc[0];
}

// Reduce 16 per-lane partials; lane l ends with sum of acc[brev4(l&15)].
__device__ __forceinline__ float tree_reduce16(float acc[BATCH], int lane) {
  #pragma unroll
  for (int k = 0; k < 8; ++k) {
    const bool hi = (lane & 1);
    const float mine = hi ? acc[k + 8] : acc[k];
    const float send = hi ? acc[k] : acc[k + 8];
    acc[k] = mine + __shfl_xor(send, 1);
  }
  #pragma unroll
  for (int k = 0; k < 4; ++k) {
    const bool hi = (lane & 2);
    const float mine = hi ? acc[k + 4] : acc[k];
    const float send = hi ? acc[k] : acc[k + 4];
    acc[k] = mine + __shfl_xor(send, 2);
  }
  #pragma unroll
  for (int k = 0; k < 2; ++k) {
    const bool hi = (lane & 4);
    const float mine = hi ? acc[k + 2] : acc[k];
    const float send = hi ? acc[k] : acc[k + 2];
    acc[k] = mine + __shfl_xor(send, 4);
  }
  {
    const bool hi = (lane & 8);
    const float mine = hi ? acc[1] : acc[0];
    const float send = hi ? acc[0] : acc[1];
    acc[0] = mine + __shfl_xor(send, 8);
  }
  acc[0] += __shfl_xor(acc[0], 16);
  acc[0] += __shfl_xor(acc[0], 32);
  return acc[0];
}

// ws: pv[512][16] f (block-major), pi[512][16] i, pre4[64] f, hnw[16] f,
//     cross[16][16] f, flag int

// Kernel A (grid 1024): blocks [0,512) score steps 0-7 (rows ≡ bloc mod 512),
// [512,1024) steps 8-15. 8 h-vectors/thread in regs (64 VGPR), no spill.
__global__ __launch_bounds__(256, 2) void score_k(
    const float* __restrict__ h_t, const float* __restrict__ feat,
    const float* __restrict__ adj, const int* __restrict__ num_nodes,
    float* __restrict__ pv, int* __restrict__ pi, float* __restrict__ pre4,
    float* __restrict__ hnw, float* __restrict__ cross)
{
  const int b = blockIdx.x;
  const int half = b >> 9;        // 0: steps 0-7, 1: steps 8-15
  const int bloc = b & 511;
  const int soff = half * 8;
  const int tid = threadIdx.x;
  const int wave = tid >> 6, lane = tid & 63;
  const int n0 = *num_nodes;

  __shared__ float sv[4][8]; __shared__ int si[4][8];
  __shared__ float red4[4];

  // this lane's 8-float slice of its half's 8 h vectors (64 VGPRs)
  float4 hA[8], hB[8];
  #pragma unroll
  for (int i = 0; i < 8; ++i) {
    const float4* hp = (const float4*)(h_t + (i + soff) * FEATD + lane * 8);
    hA[i] = hp[0]; hB[i] = hp[1];
  }

  // score phase: rows ≡ bloc (mod 512); no LDS in the inner loop
  float bestv = -FLT_MAX; int besti = 0x7fffffff;  // lane tracks step brev3(lane&7)
  #pragma unroll
  for (int j = 0; j < 4; ++j) {
    const int row = bloc + ((j * 4 + wave) << 9);  // ascending per wave
    if (row >= n0) break;
    const float4* fr = (const float4*)(feat + (size_t)row * FEATD + lane * 8);
    const float4 a0 = fr[0], a1 = fr[1];
    float acc[8];
    #pragma unroll
    for (int i = 0; i < 8; ++i) acc[i] = dot8(a0, a1, hA[i], hB[i]);
    float sq = dot8(a0, a1, a0, a1);
    #pragma unroll
    for (int m = 1; m <= 32; m <<= 1) sq += __shfl_xor(sq, m);
    const float dtot = tree_reduce8(acc, lane);
    const float v = dtot / fmaxf(sqrtf(sq), EPS_C);
    if (v > bestv) { bestv = v; besti = row; }  // strict >: lowest row wins
  }
  if (lane < 8) { sv[wave][brev3(lane)] = bestv; si[wave][brev3(lane)] = besti; }
  __syncthreads();
  if (tid < 8) {
    float v = sv[0][tid]; int ix = si[0][tid];
    #pragma unroll
    for (int w = 1; w < 4; ++w)
      if (sv[w][tid] > v || (sv[w][tid] == v && si[w][tid] < ix)) { v = sv[w][tid]; ix = si[w][tid]; }
    pv[bloc * 16 + soff + tid] = v; pi[bloc * 16 + soff + tid] = ix;  // block-major
  }

  // extra duties (half 0 only)
  if (b < 64) {
    // quarter-rowsum of adjacency row n0 + (b>>2), quarter (b&3)
    const int row = min(n0 + (b >> 2), MEMN - 1);
    const float4* r4 = (const float4*)(adj + (size_t)row * MEMN + (size_t)(b & 3) * 2048);
    const float4 q0 = r4[tid], q1 = r4[tid + 256];
    float s = q0.x+q0.y+q0.z+q0.w + q1.x+q1.y+q1.z+q1.w;
    #pragma unroll
    for (int m = 1; m <= 32; m <<= 1) s += __shfl_xor(s, m);
    if (lane == 0) red4[wave] = s;
    __syncthreads();
    if (tid == 0) pre4[b] = red4[0] + red4[1] + red4[2] + red4[3];
  } else if (b >= 64 && b < 80) {
    // cross-sims column j and ||h_j||; h[0..7] from regs, h[8..15] from L2-hot h_t
    const int j = b - 64;
    if (wave == 0) {
      const float4* cp = (const float4*)(h_t + j * FEATD + lane * 8);
      const float4 c0 = cp[0], c1 = cp[1];
      float acc[BATCH];
      #pragma unroll
      for (int i = 0; i < 8; ++i) acc[i] = dot8(c0, c1, hA[i], hB[i]);
      #pragma unroll
      for (int i = 8; i < 16; ++i) {
        const float4* bp = (const float4*)(h_t + i * FEATD + lane * 8);
        acc[i] = dot8(c0, c1, bp[0], bp[1]);
      }
      const float d = tree_reduce16(acc, lane);   // lane holds dot(h_brev4(lane), h_j)
      const float djj = __shfl(d, brev4(j));
      const float inv = 1.f / fmaxf(sqrtf(djj), EPS_C);
      if (lane == 0) hnw[j] = sqrtf(djj);
      if (lane < BATCH) cross[brev4(lane) * 16 + j] = d * inv;
    }
  }
}

// Kernel B (1 block, SMALL — no fallback body): final argmax + validation.
// Writes out[] if speculation valid, and *flag (0 valid / 1 fallback).
__global__ __launch_bounds__(256) void val_k(
    const float* __restrict__ posin, const unsigned char* __restrict__ dones,
    const int* __restrict__ lastv, const float* __restrict__ posns,
    const float* __restrict__ adj, const int* __restrict__ num_nodes,
    const float* __restrict__ pv, const int* __restrict__ pi,
    const float* __restrict__ pre4, const float* __restrict__ hn,
    const float* __restrict__ cross, float* __restrict__ out,
    int* __restrict__ flag) {
  const int tid = threadIdx.x;
  const int wave = tid >> 6, lane = tid & 63;
  __shared__ float wv[BATCH][4]; __shared__ int wi[BATCH][4];
  __shared__ float preS[BATCH]; __shared__ float s_outv[BATCH];
  __shared__ int s_valid;
  const int n0 = *num_nodes;

  // prefetch speculative adjacency probes (overlaps everything below)
  float adjval = 1.f; int lastp = -1;
  if (tid < BATCH) {
    lastp = lastv[tid];
    if (lastp != -1) {
      const int lc = min(max(lastp, 0), MEMN - 1);
      adjval = adj[(size_t)min(n0 + tid, MEMN - 1) * MEMN + lc];
    }
  }
  if (tid < BATCH)
    preS[tid] = pre4[tid*4+0] + pre4[tid*4+1] + pre4[tid*4+2] + pre4[tid*4+3];

  // thread t folds blocks t and t+256 (block-major layout -> float4/int4 loads)
  float v[BATCH]; int ix[BATCH];
  {
    const float4* pா = (const float4*)(pv + tid * 16);
    const float4* pB = (const float4*)(pv + (tid + 256) * 16);
    const int4*   qA = (const int4*)(pi + tid * 16);
    const int4*   qB = (const int4*)(pi + (tid + 256) * 16);
    #pragma unroll
    for (int q = 0; q < 4; ++q) {
      const float4 a = pா[q], c = pB[q];
      const int4   ia = qA[q], ic = qB[q];
      const float av[4] = {a.x, a.y, a.z, a.w}, cv4[4] = {c.x, c.y, c.z, c.w};
      const int   iv[4] = {ia.x, ia.y, ia.z, ia.w}, jv[4] = {ic.x, ic.y, ic.z, ic.w};
      #pragma unroll
      for (int e = 0; e < 4; ++e) {
        const int s = q * 4 + e;
        if (cv4[e] > av[e] || (cv4[e] == av[e] && jv[e] < iv[e])) { v[s] = cv4[e]; ix[s] = jv[e]; }
        else                                                      { v[s] = av[e]; ix[s] = iv[e]; }
      }
    }
  }
  #pragma unroll
  for (int s = 0; s < BATCH; ++s) {
    float bv = v[s]; int bi = ix[s];
    #pragma unroll
    for (int off = 32; off; off >>= 1) {
      const float v2 = __shfl_down(bv, off);
      const int   i2 = __shfl_down(bi, off);
      if (v2 > bv || (v2 == bv && i2 < bi)) { bv = v2; bi = i2; }
    }
    if (lane == 0) { wv[s][wave] = bv; wi[s][wave] = bi; }
  }
  __syncthreads();
  int ok = 1;
  if (tid < BATCH) {
    const int s = tid;
    float bv = wv[s][0]; int bi = wi[s][0];
    #pragma unroll
    for (int w = 1; w < 4; ++w)
      if (wv[s][w] > bv || (wv[s][w] == bv && wi[s][w] < bi)) { bv = wv[s][w]; bi = wi[s][w]; }
    for (int j = 0; j < s; ++j) {  // speculative new rows n0+j (higher idx: strict >)
      const float cv2 = cross[s * 16 + j];
      if (cv2 > bv) { bv = cv2; bi = n0 + j; }
    }
    if (bi == 0x7fffffff) ok = 0;
    else {
      const float max_sim = bv / fmaxf(hn[s], EPS_C);
      float px, py, pz;
      if (bi >= n0) { const float* pp = posin + (size_t)(bi - n0) * 3; px = pp[0]; py = pp[1]; pz = pp[2]; }
      else          { const float* pp = posns + (size_t)bi * 3;        px = pp[0]; py = pp[1]; pz = pp[2]; }
      const float dx = posin[s * 3 + 0] - px;
      const float dy = posin[s * 3 + 1] - py;
      const float dz = posin[s * 3 + 2] - pz;
      const float dist = sqrtf(dx * dx + dy * dy + dz * dz);
      const bool should_add = (max_sim < TAU_NEW_C) || (dist > D_MIN_C);
      // validity also needs lastv[s] < n0 so prior edges provably never touch row n0+s
      ok = (!dones[s]) && should_add && (lastp == -1 || lastp < n0);
      float o = preS[s];
      if (lastp != -1 && lastp != n0 + s) { if (adjval == 0.f) o += 1.f; }
      s_outv[s] = o;
    }
  }
  const unsigned long long m = __ballot(tid < BATCH ? ok : 1);
  if (tid == 0) {
    const int valid = ((~m == 0ull) && (n0 >= 1) && (n0 + BATCH <= MEMN)) ? 1 : 0;
    s_valid = valid;
    *flag = valid ? 0 : 1;
  }
  __syncthreads();
  if (s_valid && tid < BATCH) out[tid] = s_outv[tid];
}

// Kernel C (1 block): generic sequential fallback; early-exits when valid.
__global__ __launch_bounds__(256) void seq_fallback_k(
    const float* __restrict__ h_t, const float* __restrict__ posin,
    const unsigned char* __restrict__ dones, const int* __restrict__ lastv,
    const float* __restrict__ feat, const float* __restrict__ posns,
    const float* __restrict__ adj, const int* __restrict__ num_nodes,
    const int* __restrict__ ptr_in, const float* __restrict__ pre4,
    const float* __restrict__ hnv, float* __restrict__ out,
    const int* __restrict__ flag) {
  if (*flag == 0) return;
  const int tid = threadIdx.x;
  const int wave = tid >> 6, lane = tid & 63;
  __shared__ float mf[16][FEATD];
  __shared__ float mp[16][3];
  __shared__ int   midx[16];
  __shared__ float sh[FEATD];
  __shared__ float rv[256]; __shared__ int ri[256];
  __shared__ float preS[BATCH];
  __shared__ int   edges[64][2];
  __shared__ int   s_n, s_p, s_ec, s_mc;
  __shared__ int   s_done, s_widx, s_ema, s_src, s_dst, s_fb;
  __shared__ float s_delta, s_sum;
  if (tid == 0) { s_n = *num_nodes; s_p = *ptr_in; s_ec = 0; s_mc = 0; }
  if (tid < BATCH)
    preS[tid] = pre4[tid*4+0] + pre4[tid*4+1] + pre4[tid*4+2] + pre4[tid*4+3];
  const int n0 = *num_nodes;
  __syncthreads();

  for (int step = 0; step < BATCH; ++step) {
    for (int k = tid; k < FEATD; k += 256) sh[k] = h_t[step * FEATD + k];
    __syncthreads();
    const int n_cur = s_n, mc = s_mc;

    float bv = -FLT_MAX; int bi = 0x7fffffff;
    for (int r = wave; r < n_cur; r += 4) {  // ascending per wave
      const float* src = feat + (size_t)r * FEATD;
      for (int k = 0; k < 16; ++k)
        if (k < mc && midx[k] == r) src = mf[k];
      float dot = 0.f, sq2 = 0.f;
      for (int e = lane; e < FEATD; e += 64) {
        const float a = src[e], b2 = sh[e];
        dot += a * b2; sq2 += a * a;
      }
      #pragma unroll
      for (int off = 32; off; off >>= 1) {
        dot += __shfl_down(dot, off);
        sq2 += __shfl_down(sq2, off);
      }
      if (lane == 0) {
        const float vv = dot / fmaxf(sqrtf(sq2), EPS_C);
        if (vv > bv) { bv = vv; bi = r; }
      }
    }
    if (lane == 0) { rv[wave] = bv; ri[wave] = bi; }
    __syncthreads();

    if (tid == 0) {
      float fbv = rv[0]; int fbi = ri[0];
      for (int w = 1; w < 4; ++w)
        if (rv[w] > fbv || (rv[w] == fbv && ri[w] < fbi)) { fbv = rv[w]; fbi = ri[w]; }
      const int n = s_n, p = s_p;
      int best; float max_sim;
      if (n < 1) { best = 0; max_sim = -2.0f; }
      else { best = fbi; max_sim = fbv / fmaxf(hnv[step], EPS_C); }
      int bsrc = -1;
      for (int k = 0; k < s_mc; ++k) if (midx[k] == best) bsrc = k;
      float pbx, pby, pbz;
      if (bsrc >= 0) { pbx = mp[bsrc][0]; pby = mp[bsrc][1]; pbz = mp[bsrc][2]; }
      else { const float* pb = posns + (size_t)best * 3; pbx = pb[0]; pby = pb[1]; pbz = pb[2]; }
      const float dx = posin[step * 3 + 0] - pbx;
      const float dy = posin[step * 3 + 1] - pby;
      const float dz = posin[step * 3 + 2] - pbz;
      const float dist = sqrtf(dx * dx + dy * dy + dz * dz);
      const int done = dones[step] ? 1 : 0;
      const bool empty = (n < 1);
      const bool should_add = (max_sim < TAU_NEW_C) || (dist > D_MIN_C);
      const bool has_room = (n < MEMN);
      const int widx = empty ? 0 : (should_add ? (has_room ? n : p) : best);
      const bool ema = (!empty) && (!should_add);
      int srcs = -1;
      for (int k = 0; k < s_mc; ++k) if (midx[k] == widx) srcs = k;
      int dsts = srcs;
      if (!done) {
        if (srcs < 0) { dsts = s_mc; midx[dsts] = widx; s_mc = dsts + 1; }
        if (empty || (should_add && has_room)) s_n = n + 1;
        if ((!empty) && should_add && (!has_room)) s_p = (p + 1) % MEMN;
        const int last = lastv[step];
        if (last != -1 && last != widx) {
          const int lc = min(max(last, 0), MEMN - 1);
          const int ec = s_ec;
          edges[ec][0] = lc;   edges[ec][1] = widx;
          edges[ec + 1][0] = widx; edges[ec + 1][1] = lc;
          s_ec = ec + 2;
        }
      }
      s_done = done; s_widx = widx; s_ema = ema ? 1 : 0; s_src = srcs; s_dst = dsts;
      s_delta = 0.f;
      s_fb = 0;
      if (!done) {
        if (widx >= n0 && widx < n0 + BATCH) s_sum = preS[widx - n0];
        else s_fb = 1;
      }
    }
    __syncthreads();

    if (!s_done) {
      const int widx = s_widx;
      float* dstf = mf[s_dst];
      if (s_ema) {
        const float* srcf = (s_src >= 0) ? mf[s_src] : (feat + (size_t)widx * FEATD);
        for (int k = tid; k < FEATD; k += 256)
          dstf[k] = ALPHA_C * srcf[k] + (1.f - ALPHA_C) * sh[k];
      } else {
        for (int k = tid; k < FEATD; k += 256) dstf[k] = sh[k];
      }
      if (tid < 3) {
        const float sp = (s_src >= 0) ? mp[s_src][tid] : posns[(size_t)widx * 3 + tid];
        mp[s_dst][tid] = s_ema ? (ALPHA_C * sp + (1.f - ALPHA_C) * posin[step * 3 + tid])
                               : posin[step * 3 + tid];
      }
      if (tid < s_ec) {
        const int cur = widx;
        if (edges[tid][0] == cur) {
          const int c = edges[tid][1];
          bool dup = false;
          for (int e2 = 0; e2 < tid; ++e2)
            if (edges[e2][0] == cur && edges[e2][1] == c) dup = true;
          if (!dup && adj[(size_t)cur * MEMN + c] == 0.f) atomicAdd(&s_delta, 1.f);
        }
      }
    }
    __syncthreads();

    if (s_fb) {
      const float* rowp = adj + (size_t)s_widx * MEMN;
      float s = 0.f;
      for (int k = tid; k < MEMN; k += 256) s += rowp[k];
      rv[tid] = s;
      __syncthreads();
      for (int st = 128; st; st >>= 1) { if (tid < st) rv[tid] += rv[tid + st]; __syncthreads(); }
      if (tid == 0) s_sum = rv[0];
      __syncthreads();
    }
    if (tid == 0) out[step] = s_done ? 0.f : (s_sum + s_delta);
    __syncthreads();
  }
}

extern "C" void kernel_launch(void* const* d_in, const int* in_sizes, int n_in,
                              void* d_out, int out_size, void* d_ws, size_t ws_size,
                              hipStream_t stream) {
  const float*         h_t       = (const float*)d_in[0];
  const float*         cur_pos   = (const float*)d_in[1];
  const unsigned char* dones     = (const unsigned char*)d_in[2];
  const float*         node_feat = (const float*)d_in[3];
  const float*         node_pos  = (const float*)d_in[4];
  const float*         adj       = (const float*)d_in[5];
  const int*           num_nodes = (const int*)d_in[6];
  const int*           ptr_in    = (const int*)d_in[7];
  const int*           lastv     = (const int*)d_in[8];
  float* out = (float*)d_out;

  float* pv    = (float*)d_ws;               // [512][16] block-major
  int*   pi    = (int*)(pv + 512 * 16);      // [512][16]
  float* pre4  = (float*)(pi + 512 * 16);    // 64
  float* hnw   = pre4 + 64;                  // 16
  float* cross = hnw + BATCH;                // 256
  int*   flag  = (int*)(cross + 256);        // 1

  score_k<<<1024, 256, 0, stream>>>(h_t, node_feat, adj, num_nodes, pv, pi, pre4, hnw, cross);
  val_k<<<1, 256, 0, stream>>>(cur_pos, dones, lastv, node_pos, adj, num_nodes,
                               pv, pi, pre4, hnw, cross, out, flag);
  seq_fallback_k<<<1, 256, 0, stream>>>(h_t, cur_pos, dones, lastv, node_feat, node_pos,
                                        adj, num_nodes, ptr_in, pre4, hnw, out, flag);
}